// Round 9
// baseline (335.799 us; speedup 1.0000x reference)
//
#include <hip/hip_runtime.h>

// out[b,c] = mask[c] * (U @ X @ U^T),  U[n][h] = sum_k DH2[k][n]*DH[k][h]  (128x64)
// Stage 1: R = X @ U^T  (K=w, row-major X feeds MFMA A directly),
// Stage 2: out = U @ R  (K=h, R staged in LDS as [m][h] hi/lo fp16).
// fp16 2-term split (hi+lo), 3 MFMA passes -> ~2^-22 relative error.
// r7: dropped the sOutW store bounce (direct 64B-segment dword stores),
//     LDS 71KB -> 37KB -> 4 blocks/CU, stores interleaved with stage-2 MFMAs.

typedef __attribute__((ext_vector_type(8))) _Float16 f16x8;
typedef __attribute__((ext_vector_type(4))) _Float16 f16x4;
typedef __attribute__((ext_vector_type(4))) float f32x4;

#define NSLICES 4096
#define MFMA16(A, B, C) __builtin_amdgcn_mfma_f32_16x16x32_f16((A), (B), (C), 0, 0, 0)

// ---------------------------------------------------------------------------
// Build U in MFMA fragment-dump order, fp16 hi/lo.
// Fragment (tile j=0..7, kk=0..1, hl=0..1) = 512 halfs; lane l holds 8 halfs:
//   value = U[16*j + (l&15)][32*kk + 8*(l>>4) + t],  t = 0..7
// Same table serves stage-1 B (index by m-tile) and stage-2 A (index by n-tile).
// ---------------------------------------------------------------------------
__global__ void build_ut(_Float16* __restrict__ uf) {
    const int idx = blockIdx.x * 256 + threadIdx.x;  // 0..8191
    const int n = idx >> 6;   // 0..127 (U row)
    const int h = idx & 63;   // 0..63  (U col)
    const float s0 = 0.125f;                 // sqrt(1/64)
    const float sk = 0.17677669529663687f;   // sqrt(2/64)
    const float t0 = 0.088388347648318447f;  // sqrt(1/128)
    const float tk = 0.125f;                 // sqrt(2/128)
    float acc = s0 * t0;
    #pragma unroll 4
    for (int k = 1; k < 64; ++k) {
        float a = cospif((float)((2 * h + 1) * k) * (1.0f / 128.0f));
        float b = cospif((float)((2 * n + 1) * k) * (1.0f / 256.0f));
        acc = fmaf(sk * tk * a, b, acc);
    }
    _Float16 hi = (_Float16)acc;
    _Float16 lo = (_Float16)(acc - (float)hi);
    const int j = n >> 4;
    const int lane = (n & 15) + 16 * ((h >> 3) & 3);
    const int kk = h >> 5;
    const int t = h & 7;
    const int base = ((j * 2 + kk) * 2) * 512 + lane * 8 + t;
    uf[base] = hi;         // hl = 0
    uf[base + 512] = lo;   // hl = 1
}

// ---------------------------------------------------------------------------
// One block = one (b,c) slice. 256 threads = 4 waves.
// Stage 1: R[h][m] = sum_w X[h][w] * U[m][w]   (wave wid owns h-tile wid)
// Stage 2: out[n][m] = sum_h U[n][h] * R[h][m] (wave wid owns n-tiles 2wid,2wid+1)
// LDS: sRh/sRl [128][72] fp16 (pad 8 -> 2-way banks, 16B-aligned b128 reads).
// 36.9KB LDS -> 4 blocks/CU (16 waves/CU).
// Epilogue: direct dword stores from the C/D frag — per instruction each
// 16-lane group writes one contiguous 64B segment; over the j-loop each row
// receives contiguous 512B, merged to full lines in L2.
// ---------------------------------------------------------------------------
__global__ __launch_bounds__(256, 4)
void dct_fsr(const float* __restrict__ x, const float* __restrict__ mask,
             const _Float16* __restrict__ uf, float* __restrict__ out) {
    __shared__ _Float16 sRh[128 * 72];
    __shared__ _Float16 sRl[128 * 72];

    const int tid = threadIdx.x;
    const int wid = tid >> 6;
    const int lane = tid & 63;
    const int l15 = lane & 15;
    const int lg = lane >> 4;  // 0..3
    const int slice = blockIdx.x;
    const float mval = mask[slice & 255];

    const f16x8* ufr = (const f16x8*)uf;  // [frag*64 + lane]

    // ---- A-frags for stage 1: X rows (16*wid + l15), 8 contiguous w per lane ----
    const float* xp = x + (size_t)slice * 4096 + (16 * wid + l15) * 64 + 8 * lg;
    const float4 xa = *(const float4*)xp;          // kk=0, t=0..3
    const float4 xb = *(const float4*)(xp + 4);    // kk=0, t=4..7
    const float4 xc = *(const float4*)(xp + 32);   // kk=1, t=0..3
    const float4 xd = *(const float4*)(xp + 36);   // kk=1, t=4..7

    f16x8 ah0, al0, ah1, al1;
#define SPLIT(H, L, E, V)                      \
    {                                          \
        float y_ = (V) * mval;                 \
        _Float16 h_ = (_Float16)y_;            \
        H[E] = h_;                             \
        L[E] = (_Float16)(y_ - (float)h_);     \
    }
    SPLIT(ah0, al0, 0, xa.x) SPLIT(ah0, al0, 1, xa.y)
    SPLIT(ah0, al0, 2, xa.z) SPLIT(ah0, al0, 3, xa.w)
    SPLIT(ah0, al0, 4, xb.x) SPLIT(ah0, al0, 5, xb.y)
    SPLIT(ah0, al0, 6, xb.z) SPLIT(ah0, al0, 7, xb.w)
    SPLIT(ah1, al1, 0, xc.x) SPLIT(ah1, al1, 1, xc.y)
    SPLIT(ah1, al1, 2, xc.z) SPLIT(ah1, al1, 3, xc.w)
    SPLIT(ah1, al1, 4, xd.x) SPLIT(ah1, al1, 5, xd.y)
    SPLIT(ah1, al1, 6, xd.z) SPLIT(ah1, al1, 7, xd.w)
#undef SPLIT

    // ---- stage 1: per m-tile j, D = X_tile * U^T_tile, 3 passes ----
    #pragma unroll
    for (int j = 0; j < 8; ++j) {
        const f16x8 bh0 = ufr[((j * 2 + 0) * 2 + 0) * 64 + lane];
        const f16x8 bl0 = ufr[((j * 2 + 0) * 2 + 1) * 64 + lane];
        const f16x8 bh1 = ufr[((j * 2 + 1) * 2 + 0) * 64 + lane];
        const f16x8 bl1 = ufr[((j * 2 + 1) * 2 + 1) * 64 + lane];
        f32x4 acc = {0.f, 0.f, 0.f, 0.f};
        acc = MFMA16(ah0, bh0, acc);
        acc = MFMA16(ah1, bh1, acc);
        acc = MFMA16(ah0, bl0, acc);
        acc = MFMA16(ah1, bl1, acc);
        acc = MFMA16(al0, bh0, acc);
        acc = MFMA16(al1, bh1, acc);
        // D frag: col m = 16j+l15, rows h = 16*wid + 4*lg + r  -> sR[m][h]
        const int m = 16 * j + l15;
        const int h0 = 16 * wid + 4 * lg;
        f16x4 rh, rl;
        #pragma unroll
        for (int r = 0; r < 4; ++r) {
            const float vv = acc[r];
            const _Float16 hi = (_Float16)vv;
            rh[r] = hi;
            rl[r] = (_Float16)(vv - (float)hi);
        }
        *(f16x4*)&sRh[m * 72 + h0] = rh;
        *(f16x4*)&sRl[m * 72 + h0] = rl;
    }
    __syncthreads();

    // ---- stage 2: out tiles (n-tile ig = 2*wid+i, m-tile j), direct stores ----
    float* og = out + (size_t)slice * 16384;  // 128*128
    #pragma unroll
    for (int i = 0; i < 2; ++i) {
        const int ig = 2 * wid + i;
        const f16x8 Ah0 = ufr[((ig * 2 + 0) * 2 + 0) * 64 + lane];
        const f16x8 Al0 = ufr[((ig * 2 + 0) * 2 + 1) * 64 + lane];
        const f16x8 Ah1 = ufr[((ig * 2 + 1) * 2 + 0) * 64 + lane];
        const f16x8 Al1 = ufr[((ig * 2 + 1) * 2 + 1) * 64 + lane];
        float* orow = og + (size_t)(16 * ig + 4 * lg) * 128 + l15;
        #pragma unroll
        for (int j = 0; j < 8; ++j) {
            const int m = 16 * j + l15;
            const f16x8 bh0 = *(const f16x8*)&sRh[m * 72 + 0 + 8 * lg];
            const f16x8 bh1 = *(const f16x8*)&sRh[m * 72 + 32 + 8 * lg];
            const f16x8 bl0 = *(const f16x8*)&sRl[m * 72 + 0 + 8 * lg];
            const f16x8 bl1 = *(const f16x8*)&sRl[m * 72 + 32 + 8 * lg];
            f32x4 a = {0.f, 0.f, 0.f, 0.f};
            a = MFMA16(Ah0, bh0, a);
            a = MFMA16(Ah1, bh1, a);
            a = MFMA16(Ah0, bl0, a);
            a = MFMA16(Ah1, bl1, a);
            a = MFMA16(Al0, bh0, a);
            a = MFMA16(Al1, bh1, a);
            // store: row n = 16ig + 4lg + r, col m = 16j + l15
            // per (r): each 16-lane group writes a contiguous 64B segment
            #pragma unroll
            for (int r = 0; r < 4; ++r)
                orow[(size_t)r * 128 + 16 * j] = a[r];
        }
    }
}

extern "C" void kernel_launch(void* const* d_in, const int* in_sizes, int n_in,
                              void* d_out, int out_size, void* d_ws, size_t ws_size,
                              hipStream_t stream) {
    const float* x = (const float*)d_in[0];      // [16,256,64,64] fp32
    const float* mask = (const float*)d_in[1];   // [1,256,1,1] fp32
    float* out = (float*)d_out;                  // [16,256,128,128] fp32
    _Float16* uf = (_Float16*)d_ws;              // 16384 halfs = 32KB

    build_ut<<<32, 256, 0, stream>>>(uf);
    dct_fsr<<<NSLICES, 256, 0, stream>>>(x, mask, uf, out);
}